// Round 1
// baseline (573.051 us; speedup 1.0000x reference)
//
#include <hip/hip_runtime.h>

typedef __attribute__((ext_vector_type(8))) short short8;
typedef __attribute__((ext_vector_type(4))) float floatx4;

__device__ __forceinline__ unsigned short f2bf(float f) {
    union { float f; unsigned int u; } v; v.f = f;
    unsigned int u = v.u;
    unsigned int r = (u + 0x7FFFu + ((u >> 16) & 1u)) >> 16;
    return (unsigned short)r;
}

// ---------------- convert x (fp32 -> bf16), 4 elems/thread ----------------
__global__ __launch_bounds__(256) void cvt_x(const float* __restrict__ src,
                                             unsigned short* __restrict__ dst, int n4) {
    int i = blockIdx.x * blockDim.x + threadIdx.x;
    if (i < n4) {
        float4 v = ((const float4*)src)[i];
        union { unsigned short s[4]; int2 p; } o;
        o.s[0] = f2bf(v.x); o.s[1] = f2bf(v.y); o.s[2] = f2bf(v.z); o.s[3] = f2bf(v.w);
        ((int2*)dst)[i] = o.p;
    }
}

// ------------- transpose + convert: src[R][C] fp32 -> dst[C][R] bf16 -------------
__global__ __launch_bounds__(256) void transpose_bf16(const float* __restrict__ src,
                                                      unsigned short* __restrict__ dst,
                                                      int R, int C) {
    __shared__ float tile[32][33];
    int c0 = blockIdx.x * 32, r0 = blockIdx.y * 32;
    int tc = threadIdx.x & 31, tr = (threadIdx.x >> 5) * 4;
#pragma unroll
    for (int i = 0; i < 4; ++i)
        tile[tr + i][tc] = src[(size_t)(r0 + tr + i) * C + c0 + tc];
    __syncthreads();
#pragma unroll
    for (int i = 0; i < 4; ++i)
        dst[(size_t)(c0 + tr + i) * R + r0 + tc] = f2bf(tile[tc][tr + i]);
}

// ---------------- bf16 MFMA GEMM: C[M][N] = A[M][K] * Bt[N][K]^T ----------------
// 128x128 tile, BK=32, 256 threads (4 waves, 2x2), each wave 64x64 via 4x4 MFMA tiles.
template <bool OUT_BF16>
__global__ __launch_bounds__(256) void gemm_bt(const unsigned short* __restrict__ A,
                                               const unsigned short* __restrict__ Bt,
                                               void* __restrict__ Cout,
                                               int M, int N, int K) {
    __shared__ unsigned short Asm[128][48];  // stride 48 elems = 96 B (16B aligned)
    __shared__ unsigned short Bsm[128][48];

    const int tid = threadIdx.x;
    const int wave = tid >> 6, lane = tid & 63, quad = lane >> 4, l15 = lane & 15;
    const int wm = wave >> 1, wn = wave & 1;
    const int bm = blockIdx.y * 128, bn = blockIdx.x * 128;

    floatx4 acc[4][4];
    const floatx4 z = {0.f, 0.f, 0.f, 0.f};
#pragma unroll
    for (int mi = 0; mi < 4; ++mi)
#pragma unroll
        for (int ni = 0; ni < 4; ++ni) acc[mi][ni] = z;

    const int arow = tid >> 1, ahalf = (tid & 1) * 16;
    const unsigned short* Aptr = A + (size_t)(bm + arow) * K + ahalf;
    const unsigned short* Bptr = Bt + (size_t)(bn + arow) * K + ahalf;

    for (int k0 = 0; k0 < K; k0 += 32) {
        int4 a0 = *(const int4*)(Aptr + k0);
        int4 a1 = *(const int4*)(Aptr + k0 + 8);
        int4 b0 = *(const int4*)(Bptr + k0);
        int4 b1 = *(const int4*)(Bptr + k0 + 8);
        *(int4*)&Asm[arow][ahalf]     = a0;
        *(int4*)&Asm[arow][ahalf + 8] = a1;
        *(int4*)&Bsm[arow][ahalf]     = b0;
        *(int4*)&Bsm[arow][ahalf + 8] = b1;
        __syncthreads();

        short8 af[4], bfr[4];
#pragma unroll
        for (int mi = 0; mi < 4; ++mi)
            af[mi] = *(const short8*)&Asm[wm * 64 + mi * 16 + l15][quad * 8];
#pragma unroll
        for (int ni = 0; ni < 4; ++ni)
            bfr[ni] = *(const short8*)&Bsm[wn * 64 + ni * 16 + l15][quad * 8];
#pragma unroll
        for (int mi = 0; mi < 4; ++mi)
#pragma unroll
            for (int ni = 0; ni < 4; ++ni)
                acc[mi][ni] = __builtin_amdgcn_mfma_f32_16x16x32_bf16(af[mi], bfr[ni], acc[mi][ni], 0, 0, 0);
        __syncthreads();
    }

#pragma unroll
    for (int mi = 0; mi < 4; ++mi)
#pragma unroll
        for (int ni = 0; ni < 4; ++ni)
#pragma unroll
            for (int r = 0; r < 4; ++r) {
                int row = bm + wm * 64 + mi * 16 + quad * 4 + r;
                int col = bn + wn * 64 + ni * 16 + l15;
                if (OUT_BF16)
                    ((unsigned short*)Cout)[(size_t)row * N + col] = f2bf(acc[mi][ni][r]);
                else
                    ((float*)Cout)[(size_t)row * N + col] = acc[mi][ni][r];
            }
}

// ---------------- sliding-window flash attention ----------------
// qkv: [B*N][3072] bf16 (q|k|v each 1024 = 16 heads * 64). Grid (nb=16, BH=64).
// Block: 256 threads = 4 waves, each wave 64 queries. Chunks of 64 keys, window 512.
__global__ __launch_bounds__(256) void attn_swin(const unsigned short* __restrict__ qkv,
                                                 unsigned short* __restrict__ attn_out) {
    __shared__ unsigned short Klds[64][80];      // [key][d], stride 80 (160 B)
    __shared__ unsigned short Vt[64][80];        // [d][key]
    __shared__ unsigned short Plds[4][64][80];   // per-wave [q][key]

    const int blk = blockIdx.x, bh = blockIdx.y;
    const int b = bh >> 4, h = bh & 15;
    const int tid = threadIdx.x;
    const int wave = tid >> 6, lane = tid & 63, quad = lane >> 4, l15 = lane & 15;
    const int qi_base = blk * 256 + wave * 64;
    const size_t seqbase = (size_t)b * 4096;

    floatx4 o[4][4];
    const floatx4 z = {0.f, 0.f, 0.f, 0.f};
    float m_run[4][4], l_run[4][4];
#pragma unroll
    for (int mi = 0; mi < 4; ++mi) {
#pragma unroll
        for (int ni = 0; ni < 4; ++ni) o[mi][ni] = z;
#pragma unroll
        for (int r = 0; r < 4; ++r) { m_run[mi][r] = -1.0e30f; l_run[mi][r] = 0.f; }
    }

    const int kwin0 = blk * 256 - 256;
    const int sk_key = tid >> 2, sk_g = (tid & 3) * 16;
    const int sv_key = tid & 63, sv_dg = (tid >> 6) * 16;

    for (int c = 0; c < 8; ++c) {
        const int k0 = kwin0 + c * 64;
        __syncthreads();  // previous chunk's LDS reads done before restaging
        {   // stage K chunk [64][64]
            int kabs = k0 + sk_key;
            int4 v0 = {0, 0, 0, 0}, v1 = {0, 0, 0, 0};
            if (kabs >= 0) {
                const int4* s = (const int4*)(qkv + (seqbase + kabs) * 3072 + 1024 + h * 64 + sk_g);
                v0 = s[0]; v1 = s[1];
            }
            *(int4*)&Klds[sk_key][sk_g]     = v0;
            *(int4*)&Klds[sk_key][sk_g + 8] = v1;
        }
        {   // stage V chunk transposed -> Vt[d][key]
            int kabs = k0 + sv_key;
            int4 t0 = {0, 0, 0, 0}, t1 = {0, 0, 0, 0};
            if (kabs >= 0) {
                const int4* s = (const int4*)(qkv + (seqbase + kabs) * 3072 + 2048 + h * 64 + sv_dg);
                t0 = s[0]; t1 = s[1];
            }
            unsigned short tmp[16];
            *(int4*)&tmp[0] = t0; *(int4*)&tmp[8] = t1;
#pragma unroll
            for (int i = 0; i < 16; ++i) Vt[sv_dg + i][sv_key] = tmp[i];
        }
        __syncthreads();

        // ---- QK^T: s[mi][ni] = Q(64x64-chunk) . K^T ----
        floatx4 s[4][4];
#pragma unroll
        for (int mi = 0; mi < 4; ++mi)
#pragma unroll
            for (int ni = 0; ni < 4; ++ni) s[mi][ni] = z;
#pragma unroll
        for (int ks = 0; ks < 2; ++ks) {
            short8 kf[4];
#pragma unroll
            for (int ni = 0; ni < 4; ++ni)
                kf[ni] = *(const short8*)&Klds[ni * 16 + l15][ks * 32 + quad * 8];
#pragma unroll
            for (int mi = 0; mi < 4; ++mi) {
                short8 qf = *(const short8*)(qkv + (seqbase + qi_base + mi * 16 + l15) * 3072
                                             + h * 64 + ks * 32 + quad * 8);
#pragma unroll
                for (int ni = 0; ni < 4; ++ni)
                    s[mi][ni] = __builtin_amdgcn_mfma_f32_16x16x32_bf16(qf, kf[ni], s[mi][ni], 0, 0, 0);
            }
        }

        // ---- scale + mask + online softmax ----
        float mrow[4][4], alpha[4][4], lsum[4][4];
#pragma unroll
        for (int mi = 0; mi < 4; ++mi)
#pragma unroll
            for (int r = 0; r < 4; ++r) mrow[mi][r] = -3.0e38f;
#pragma unroll
        for (int mi = 0; mi < 4; ++mi)
#pragma unroll
            for (int ni = 0; ni < 4; ++ni) {
                int kcol = k0 + ni * 16 + l15;
#pragma unroll
                for (int r = 0; r < 4; ++r) {
                    int qrow = qi_base + mi * 16 + quad * 4 + r;
                    float sv = s[mi][ni][r] * 0.125f;
                    bool valid = (kcol >= 0) && (kcol <= qrow) && (kcol >= qrow - 255);
                    sv = valid ? sv : -3.0e38f;
                    s[mi][ni][r] = sv;
                    mrow[mi][r] = fmaxf(mrow[mi][r], sv);
                }
            }
#pragma unroll
        for (int mi = 0; mi < 4; ++mi)
#pragma unroll
            for (int r = 0; r < 4; ++r) {
                float v = mrow[mi][r];
                v = fmaxf(v, __shfl_xor(v, 1));
                v = fmaxf(v, __shfl_xor(v, 2));
                v = fmaxf(v, __shfl_xor(v, 4));
                v = fmaxf(v, __shfl_xor(v, 8));
                float mn = fmaxf(m_run[mi][r], v);
                alpha[mi][r] = __expf(m_run[mi][r] - mn);
                m_run[mi][r] = mn;
                lsum[mi][r] = 0.f;
            }
#pragma unroll
        for (int mi = 0; mi < 4; ++mi)
#pragma unroll
            for (int ni = 0; ni < 4; ++ni)
#pragma unroll
                for (int r = 0; r < 4; ++r) {
                    float p = __expf(s[mi][ni][r] - m_run[mi][r]);
                    lsum[mi][r] += p;
                    Plds[wave][mi * 16 + quad * 4 + r][ni * 16 + l15] = f2bf(p);
                }
#pragma unroll
        for (int mi = 0; mi < 4; ++mi)
#pragma unroll
            for (int r = 0; r < 4; ++r) {
                float v = lsum[mi][r];
                v += __shfl_xor(v, 1);
                v += __shfl_xor(v, 2);
                v += __shfl_xor(v, 4);
                v += __shfl_xor(v, 8);
                l_run[mi][r] = l_run[mi][r] * alpha[mi][r] + v;
            }
#pragma unroll
        for (int mi = 0; mi < 4; ++mi)
#pragma unroll
            for (int ni = 0; ni < 4; ++ni)
#pragma unroll
                for (int r = 0; r < 4; ++r) o[mi][ni][r] *= alpha[mi][r];

        __syncthreads();  // P LDS writes visible before A-layout reads (safety)

        // ---- PV: o += P(64x64) . V(64x64) ----
#pragma unroll
        for (int ks = 0; ks < 2; ++ks) {
            short8 vf[4];
#pragma unroll
            for (int ni = 0; ni < 4; ++ni)
                vf[ni] = *(const short8*)&Vt[ni * 16 + l15][ks * 32 + quad * 8];
#pragma unroll
            for (int mi = 0; mi < 4; ++mi) {
                short8 pf = *(const short8*)&Plds[wave][mi * 16 + l15][ks * 32 + quad * 8];
#pragma unroll
                for (int ni = 0; ni < 4; ++ni)
                    o[mi][ni] = __builtin_amdgcn_mfma_f32_16x16x32_bf16(pf, vf[ni], o[mi][ni], 0, 0, 0);
            }
        }
    }

    // ---- epilogue: normalize, write attn_out[b][q][h*64+d] bf16 ----
#pragma unroll
    for (int mi = 0; mi < 4; ++mi)
#pragma unroll
        for (int ni = 0; ni < 4; ++ni)
#pragma unroll
            for (int r = 0; r < 4; ++r) {
                int qrow = qi_base + mi * 16 + quad * 4 + r;
                int d = ni * 16 + l15;
                float val = o[mi][ni][r] / l_run[mi][r];
                attn_out[(seqbase + qrow) * 1024 + h * 64 + d] = f2bf(val);
            }
}

extern "C" void kernel_launch(void* const* d_in, const int* in_sizes, int n_in,
                              void* d_out, int out_size, void* d_ws, size_t ws_size,
                              hipStream_t stream) {
    const float* x     = (const float*)d_in[0];  // [4,4096,1024]
    const float* w_qkv = (const float*)d_in[1];  // [1024,3072]
    const float* w_out = (const float*)d_in[2];  // [1024,1024]
    float* out = (float*)d_out;                  // [4,4096,1024]

    unsigned short* xb    = (unsigned short*)d_ws;                 // 16384*1024
    unsigned short* wqkvT = xb    + (size_t)16384 * 1024;          // 3072*1024
    unsigned short* woutT = wqkvT + (size_t)3072 * 1024;           // 1024*1024
    unsigned short* qkv   = woutT + (size_t)1024 * 1024;           // 16384*3072
    unsigned short* attn  = qkv   + (size_t)16384 * 3072;          // 16384*1024
    // total: 88,080,384 bf16 = 176,160,768 bytes of ws

    cvt_x<<<16384, 256, 0, stream>>>(x, xb, 4194304);
    transpose_bf16<<<dim3(96, 32), 256, 0, stream>>>(w_qkv, wqkvT, 1024, 3072);
    transpose_bf16<<<dim3(32, 32), 256, 0, stream>>>(w_out, woutT, 1024, 1024);
    gemm_bt<true><<<dim3(24, 128), 256, 0, stream>>>(xb, wqkvT, qkv, 16384, 3072, 1024);
    attn_swin<<<dim3(16, 64), 256, 0, stream>>>(qkv, attn);
    gemm_bt<false><<<dim3(8, 128), 256, 0, stream>>>(attn, woutT, out, 16384, 1024, 1024);
}

// Round 2
// 543.824 us; speedup vs baseline: 1.0537x; 1.0537x over previous
//
#include <hip/hip_runtime.h>

typedef __attribute__((ext_vector_type(8))) short short8;
typedef __attribute__((ext_vector_type(4))) float floatx4;

// int-bridge casts (generic->AS1/AS3): LDS generic addr low 32 bits = LDS offset
#define AS1(p) ((const __attribute__((address_space(1))) void*)(uintptr_t)(p))
#define AS3(p) ((__attribute__((address_space(3))) void*)(unsigned int)(uintptr_t)(p))

__device__ __forceinline__ unsigned short f2bf(float f) {
    union { float f; unsigned int u; } v; v.f = f;
    unsigned int u = v.u;
    unsigned int r = (u + 0x7FFFu + ((u >> 16) & 1u)) >> 16;
    return (unsigned short)r;
}

// ---------------- convert x (fp32 -> bf16), 4 elems/thread ----------------
__global__ __launch_bounds__(256) void cvt_x(const float* __restrict__ src,
                                             unsigned short* __restrict__ dst, int n4) {
    int i = blockIdx.x * blockDim.x + threadIdx.x;
    if (i < n4) {
        float4 v = ((const float4*)src)[i];
        union { unsigned short s[4]; int2 p; } o;
        o.s[0] = f2bf(v.x); o.s[1] = f2bf(v.y); o.s[2] = f2bf(v.z); o.s[3] = f2bf(v.w);
        ((int2*)dst)[i] = o.p;
    }
}

// ------------- transpose + convert: src[R][C] fp32 -> dst[C][R] bf16 -------------
__global__ __launch_bounds__(256) void transpose_bf16(const float* __restrict__ src,
                                                      unsigned short* __restrict__ dst,
                                                      int R, int C) {
    __shared__ float tile[32][33];
    int c0 = blockIdx.x * 32, r0 = blockIdx.y * 32;
    int tc = threadIdx.x & 31, tr = (threadIdx.x >> 5) * 4;
#pragma unroll
    for (int i = 0; i < 4; ++i)
        tile[tr + i][tc] = src[(size_t)(r0 + tr + i) * C + c0 + tc];
    __syncthreads();
#pragma unroll
    for (int i = 0; i < 4; ++i)
        dst[(size_t)(c0 + tr + i) * R + r0 + tc] = f2bf(tile[tc][tr + i]);
}

// ---------------- bf16 MFMA GEMM: C[M][N] = A[M][K] * Bt[N][K]^T ----------------
// 128x128 tile, BK=32, 256 threads. m97-style global_load_lds width-16 staging,
// unpadded stride-32 LDS (lane-ordered dst = wave-uniform base + lane*16).
template <bool OUT_BF16>
__global__ __launch_bounds__(256) void gemm_bt(const unsigned short* __restrict__ A,
                                               const unsigned short* __restrict__ Bt,
                                               void* __restrict__ Cout,
                                               int M, int N, int K) {
    __shared__ unsigned short Asm[128 * 32];
    __shared__ unsigned short Bsm[128 * 32];

    const int tid = threadIdx.x;
    const int wave = tid >> 6, lane = tid & 63, quad = lane >> 4, l15 = lane & 15;
    const int wm = wave >> 1, wn = wave & 1;
    const int bm = blockIdx.y * 128, bn = blockIdx.x * 128;

    floatx4 acc[4][4];
    const floatx4 z = {0.f, 0.f, 0.f, 0.f};
#pragma unroll
    for (int mi = 0; mi < 4; ++mi)
#pragma unroll
        for (int ni = 0; ni < 4; ++ni) acc[mi][ni] = z;

    // staging map: idx = t*256 + tid; row = idx>>2 (0..127), kcol = (idx&3)*8
    const int r0 = tid >> 2, kc = (tid & 3) * 8;
    const unsigned short* Ap0 = A + (size_t)(bm + r0) * K + kc;
    const unsigned short* Ap1 = A + (size_t)(bm + 64 + r0) * K + kc;
    const unsigned short* Bp0 = Bt + (size_t)(bn + r0) * K + kc;
    const unsigned short* Bp1 = Bt + (size_t)(bn + 64 + r0) * K + kc;
    unsigned short* Ad0 = Asm + tid * 8;
    unsigned short* Ad1 = Asm + (256 + tid) * 8;
    unsigned short* Bd0 = Bsm + tid * 8;
    unsigned short* Bd1 = Bsm + (256 + tid) * 8;

    for (int k0 = 0; k0 < K; k0 += 32) {
        __builtin_amdgcn_global_load_lds(AS1(Ap0 + k0), AS3(Ad0), 16, 0, 0);
        __builtin_amdgcn_global_load_lds(AS1(Ap1 + k0), AS3(Ad1), 16, 0, 0);
        __builtin_amdgcn_global_load_lds(AS1(Bp0 + k0), AS3(Bd0), 16, 0, 0);
        __builtin_amdgcn_global_load_lds(AS1(Bp1 + k0), AS3(Bd1), 16, 0, 0);
        __syncthreads();  // drains vmcnt (lds-DMA) per barrier semantics

        short8 af[4], bfr[4];
#pragma unroll
        for (int mi = 0; mi < 4; ++mi)
            af[mi] = *(const short8*)&Asm[(wm * 64 + mi * 16 + l15) * 32 + quad * 8];
#pragma unroll
        for (int ni = 0; ni < 4; ++ni)
            bfr[ni] = *(const short8*)&Bsm[(wn * 64 + ni * 16 + l15) * 32 + quad * 8];
#pragma unroll
        for (int mi = 0; mi < 4; ++mi)
#pragma unroll
            for (int ni = 0; ni < 4; ++ni)
                acc[mi][ni] = __builtin_amdgcn_mfma_f32_16x16x32_bf16(af[mi], bfr[ni], acc[mi][ni], 0, 0, 0);
        __syncthreads();
    }

#pragma unroll
    for (int mi = 0; mi < 4; ++mi)
#pragma unroll
        for (int ni = 0; ni < 4; ++ni)
#pragma unroll
            for (int r = 0; r < 4; ++r) {
                int row = bm + wm * 64 + mi * 16 + quad * 4 + r;
                int col = bn + wn * 64 + ni * 16 + l15;
                if (OUT_BF16)
                    ((unsigned short*)Cout)[(size_t)row * N + col] = f2bf(acc[mi][ni][r]);
                else
                    ((float*)Cout)[(size_t)row * N + col] = acc[mi][ni][r];
            }
}

// ---------------- sliding-window flash attention ----------------
// Grid (16 q-blocks, 64 b*h). 4 waves x 64 queries. Wave w only computes
// chunks c in [w, w+4] (5 of 8); chunks with k0<0 skipped entirely.
__global__ __launch_bounds__(256) void attn_swin(const unsigned short* __restrict__ qkv,
                                                 unsigned short* __restrict__ attn_out) {
    __shared__ unsigned short Klds[64][80];
    __shared__ unsigned short Vt[64][80];
    __shared__ unsigned short Plds[4][64 * 80];  // quad-XOR-swizzled columns

    const int blk = blockIdx.x, bh = blockIdx.y;
    const int b = bh >> 4, h = bh & 15;
    const int tid = threadIdx.x;
    const int wave = tid >> 6, lane = tid & 63, quad = lane >> 4, l15 = lane & 15;
    const int qi_base = blk * 256 + wave * 64;
    const size_t seqbase = (size_t)b * 4096;
    unsigned short* Pw = &Plds[wave][0];

    // hoist Q fragments (A-layout) once
    short8 qf[4][2];
#pragma unroll
    for (int mi = 0; mi < 4; ++mi)
#pragma unroll
        for (int ks = 0; ks < 2; ++ks)
            qf[mi][ks] = *(const short8*)(qkv + (seqbase + qi_base + mi * 16 + l15) * 3072
                                          + h * 64 + ks * 32 + quad * 8);

    floatx4 o[4][4];
    const floatx4 z = {0.f, 0.f, 0.f, 0.f};
    float m_run[4][4], l_run[4][4];
#pragma unroll
    for (int mi = 0; mi < 4; ++mi) {
#pragma unroll
        for (int ni = 0; ni < 4; ++ni) o[mi][ni] = z;
#pragma unroll
        for (int r = 0; r < 4; ++r) { m_run[mi][r] = -1.0e30f; l_run[mi][r] = 0.f; }
    }

    const int kwin0 = blk * 256 - 256;
    const int sk_key = tid >> 2, sk_g = (tid & 3) * 16;
    const int sv_key = tid & 63, sv_dg = (tid >> 6) * 16;
    const float SC = 0.18033688f;  // dh^-0.5 * log2(e)

    for (int c = 0; c < 8; ++c) {
        const int k0 = kwin0 + c * 64;
        __syncthreads();  // all waves done reading K/V of previous chunk
        if (k0 >= 0) {
            const int4* sk = (const int4*)(qkv + (seqbase + k0 + sk_key) * 3072 + 1024 + h * 64 + sk_g);
            *(int4*)&Klds[sk_key][sk_g]     = sk[0];
            *(int4*)&Klds[sk_key][sk_g + 8] = sk[1];
            const int4* sv = (const int4*)(qkv + (seqbase + k0 + sv_key) * 3072 + 2048 + h * 64 + sv_dg);
            int4 t0 = sv[0], t1 = sv[1];
            union { unsigned short s[16]; int4 q[2]; } tmp;
            tmp.q[0] = t0; tmp.q[1] = t1;
#pragma unroll
            for (int i = 0; i < 16; ++i) Vt[sv_dg + i][sv_key] = tmp.s[i];
        }
        __syncthreads();
        if (k0 < 0 || c < wave || c > wave + 4) continue;  // wave-uniform

        // ---- QK^T ----
        floatx4 s[4][4];
#pragma unroll
        for (int mi = 0; mi < 4; ++mi)
#pragma unroll
            for (int ni = 0; ni < 4; ++ni) s[mi][ni] = z;
#pragma unroll
        for (int ks = 0; ks < 2; ++ks) {
            short8 kf[4];
#pragma unroll
            for (int ni = 0; ni < 4; ++ni)
                kf[ni] = *(const short8*)&Klds[ni * 16 + l15][ks * 32 + quad * 8];
#pragma unroll
            for (int mi = 0; mi < 4; ++mi)
#pragma unroll
                for (int ni = 0; ni < 4; ++ni)
                    s[mi][ni] = __builtin_amdgcn_mfma_f32_16x16x32_bf16(qf[mi][ks], kf[ni], s[mi][ni], 0, 0, 0);
        }

        // ---- mask (diagonal chunks only; local indices) ----
        if (c == wave) {           // keys qi_base-256+j : valid iff j >= i+1
#pragma unroll
            for (int mi = 0; mi < 4; ++mi)
#pragma unroll
                for (int ni = 0; ni < 4; ++ni) {
                    int j = ni * 16 + l15, ib = mi * 16 + quad * 4;
#pragma unroll
                    for (int r = 0; r < 4; ++r)
                        if (j < ib + r + 1) s[mi][ni][r] = -3.0e38f;
                }
        } else if (c == wave + 4) { // keys qi_base+j : valid iff j <= i
#pragma unroll
            for (int mi = 0; mi < 4; ++mi)
#pragma unroll
                for (int ni = 0; ni < 4; ++ni) {
                    int j = ni * 16 + l15, ib = mi * 16 + quad * 4;
#pragma unroll
                    for (int r = 0; r < 4; ++r)
                        if (j > ib + r) s[mi][ni][r] = -3.0e38f;
                }
        }

        // ---- online softmax (log2 domain) ----
        float mrow[4][4], alpha[4][4], lsum[4][4];
#pragma unroll
        for (int mi = 0; mi < 4; ++mi)
#pragma unroll
            for (int r = 0; r < 4; ++r) {
                float v = s[mi][0][r];
                v = fmaxf(v, s[mi][1][r]);
                v = fmaxf(v, s[mi][2][r]);
                v = fmaxf(v, s[mi][3][r]);
                mrow[mi][r] = v;
            }
#pragma unroll
        for (int mi = 0; mi < 4; ++mi)
#pragma unroll
            for (int r = 0; r < 4; ++r) {
                float v = mrow[mi][r];
                v = fmaxf(v, __shfl_xor(v, 1));
                v = fmaxf(v, __shfl_xor(v, 2));
                v = fmaxf(v, __shfl_xor(v, 4));
                v = fmaxf(v, __shfl_xor(v, 8));
                float mn = fmaxf(m_run[mi][r], v * SC);
                alpha[mi][r] = __builtin_amdgcn_exp2f(m_run[mi][r] - mn);
                m_run[mi][r] = mn;
                lsum[mi][r] = 0.f;
            }
#pragma unroll
        for (int mi = 0; mi < 4; ++mi)
#pragma unroll
            for (int ni = 0; ni < 4; ++ni) {
                int colsw = ((ni ^ quad) << 4) + l15;  // quad-XOR swizzle: conflict-free
#pragma unroll
                for (int r = 0; r < 4; ++r) {
                    float p = __builtin_amdgcn_exp2f(fmaf(s[mi][ni][r], SC, -m_run[mi][r]));
                    lsum[mi][r] += p;
                    Pw[(mi * 16 + quad * 4 + r) * 80 + colsw] = f2bf(p);
                }
            }
#pragma unroll
        for (int mi = 0; mi < 4; ++mi)
#pragma unroll
            for (int r = 0; r < 4; ++r) {
                float v = lsum[mi][r];
                v += __shfl_xor(v, 1);
                v += __shfl_xor(v, 2);
                v += __shfl_xor(v, 4);
                v += __shfl_xor(v, 8);
                l_run[mi][r] = l_run[mi][r] * alpha[mi][r] + v;
            }
#pragma unroll
        for (int mi = 0; mi < 4; ++mi)
#pragma unroll
            for (int ni = 0; ni < 4; ++ni)
#pragma unroll
                for (int r = 0; r < 4; ++r) o[mi][ni][r] *= alpha[mi][r];

        // ---- PV (P round-trip within-wave; DS ops in-order, no barrier needed) ----
#pragma unroll
        for (int ks = 0; ks < 2; ++ks) {
            short8 vf[4];
#pragma unroll
            for (int ni = 0; ni < 4; ++ni)
                vf[ni] = *(const short8*)&Vt[ni * 16 + l15][ks * 32 + quad * 8];
#pragma unroll
            for (int mi = 0; mi < 4; ++mi) {
                short8 pf = *(const short8*)&Pw[(mi * 16 + l15) * 80
                                                + ((((2 * ks + (quad >> 1)) ^ (l15 >> 2)) << 4)
                                                   + ((quad & 1) << 3))];
#pragma unroll
                for (int ni = 0; ni < 4; ++ni)
                    o[mi][ni] = __builtin_amdgcn_mfma_f32_16x16x32_bf16(pf, vf[ni], o[mi][ni], 0, 0, 0);
            }
        }
    }

    // ---- epilogue ----
#pragma unroll
    for (int mi = 0; mi < 4; ++mi)
#pragma unroll
        for (int r = 0; r < 4; ++r) {
            float rl = __builtin_amdgcn_rcpf(l_run[mi][r]);
#pragma unroll
            for (int ni = 0; ni < 4; ++ni) {
                int qrow = qi_base + mi * 16 + quad * 4 + r;
                int d = ni * 16 + l15;
                attn_out[(seqbase + qrow) * 1024 + h * 64 + d] = f2bf(o[mi][ni][r] * rl);
            }
        }
}

extern "C" void kernel_launch(void* const* d_in, const int* in_sizes, int n_in,
                              void* d_out, int out_size, void* d_ws, size_t ws_size,
                              hipStream_t stream) {
    const float* x     = (const float*)d_in[0];  // [4,4096,1024]
    const float* w_qkv = (const float*)d_in[1];  // [1024,3072]
    const float* w_out = (const float*)d_in[2];  // [1024,1024]
    float* out = (float*)d_out;                  // [4,4096,1024]

    unsigned short* xb    = (unsigned short*)d_ws;                 // 16384*1024
    unsigned short* wqkvT = xb    + (size_t)16384 * 1024;          // 3072*1024
    unsigned short* woutT = wqkvT + (size_t)3072 * 1024;           // 1024*1024
    unsigned short* qkv   = woutT + (size_t)1024 * 1024;           // 16384*3072
    unsigned short* attn  = qkv   + (size_t)16384 * 3072;          // 16384*1024

    cvt_x<<<16384, 256, 0, stream>>>(x, xb, 4194304);
    transpose_bf16<<<dim3(96, 32), 256, 0, stream>>>(w_qkv, wqkvT, 1024, 3072);
    transpose_bf16<<<dim3(32, 32), 256, 0, stream>>>(w_out, woutT, 1024, 1024);
    gemm_bt<true><<<dim3(24, 128), 256, 0, stream>>>(xb, wqkvT, qkv, 16384, 3072, 1024);
    attn_swin<<<dim3(16, 64), 256, 0, stream>>>(qkv, attn);
    gemm_bt<false><<<dim3(8, 128), 256, 0, stream>>>(attn, woutT, out, 16384, 1024, 1024);
}

// Round 3
// 444.950 us; speedup vs baseline: 1.2879x; 1.2222x over previous
//
#include <hip/hip_runtime.h>

typedef __attribute__((ext_vector_type(8))) short short8;
typedef __attribute__((ext_vector_type(4))) float floatx4;

// int-bridge casts (generic->AS1/AS3): LDS generic addr low 32 bits = LDS offset
#define AS1(p) ((const __attribute__((address_space(1))) void*)(uintptr_t)(p))
#define AS3(p) ((__attribute__((address_space(3))) void*)(unsigned int)(uintptr_t)(p))

__device__ __forceinline__ unsigned short f2bf(float f) {
    union { float f; unsigned int u; } v; v.f = f;
    unsigned int u = v.u;
    unsigned int r = (u + 0x7FFFu + ((u >> 16) & 1u)) >> 16;
    return (unsigned short)r;
}

// pack two floats -> bf16x2 in one int (HW packed cvt if available)
__device__ __forceinline__ int pk_bf16(float a, float b) {
#if __has_builtin(__builtin_amdgcn_cvt_pk_bf16_f32)
    auto r = __builtin_amdgcn_cvt_pk_bf16_f32(a, b);
    int out; __builtin_memcpy(&out, &r, sizeof(int)); return out;
#else
    return (int)f2bf(a) | ((int)f2bf(b) << 16);
#endif
}

// ---------------- convert x (fp32 -> bf16), 4 elems/thread ----------------
__global__ __launch_bounds__(256) void cvt_x(const float* __restrict__ src,
                                             unsigned short* __restrict__ dst, int n4) {
    int i = blockIdx.x * blockDim.x + threadIdx.x;
    if (i < n4) {
        float4 v = ((const float4*)src)[i];
        int2 o = {pk_bf16(v.x, v.y), pk_bf16(v.z, v.w)};
        ((int2*)dst)[i] = o;
    }
}

// ------------- transpose + convert: src[R][C] fp32 -> dst[C][R] bf16 -------------
__global__ __launch_bounds__(256) void transpose_bf16(const float* __restrict__ src,
                                                      unsigned short* __restrict__ dst,
                                                      int R, int C) {
    __shared__ float tile[32][33];
    int c0 = blockIdx.x * 32, r0 = blockIdx.y * 32;
    int tc = threadIdx.x & 31, tr = (threadIdx.x >> 5) * 4;
#pragma unroll
    for (int i = 0; i < 4; ++i)
        tile[tr + i][tc] = src[(size_t)(r0 + tr + i) * C + c0 + tc];
    __syncthreads();
#pragma unroll
    for (int i = 0; i < 4; ++i)
        dst[(size_t)(c0 + tr + i) * R + r0 + tc] = f2bf(tile[tc][tr + i]);
}

// ---------------- bf16 MFMA GEMM: C[M][N] = A[M][K] * Bt[N][K]^T ----------------
template <bool OUT_BF16>
__global__ __launch_bounds__(256) void gemm_bt(const unsigned short* __restrict__ A,
                                               const unsigned short* __restrict__ Bt,
                                               void* __restrict__ Cout,
                                               int M, int N, int K) {
    __shared__ unsigned short Asm[128 * 32];
    __shared__ unsigned short Bsm[128 * 32];

    const int tid = threadIdx.x;
    const int wave = tid >> 6, lane = tid & 63, quad = lane >> 4, l15 = lane & 15;
    const int wm = wave >> 1, wn = wave & 1;
    const int bm = blockIdx.y * 128, bn = blockIdx.x * 128;

    floatx4 acc[4][4];
    const floatx4 z = {0.f, 0.f, 0.f, 0.f};
#pragma unroll
    for (int mi = 0; mi < 4; ++mi)
#pragma unroll
        for (int ni = 0; ni < 4; ++ni) acc[mi][ni] = z;

    const int r0 = tid >> 2, kc = (tid & 3) * 8;
    const unsigned short* Ap0 = A + (size_t)(bm + r0) * K + kc;
    const unsigned short* Ap1 = A + (size_t)(bm + 64 + r0) * K + kc;
    const unsigned short* Bp0 = Bt + (size_t)(bn + r0) * K + kc;
    const unsigned short* Bp1 = Bt + (size_t)(bn + 64 + r0) * K + kc;
    unsigned short* Ad0 = Asm + tid * 8;
    unsigned short* Ad1 = Asm + (256 + tid) * 8;
    unsigned short* Bd0 = Bsm + tid * 8;
    unsigned short* Bd1 = Bsm + (256 + tid) * 8;

    for (int k0 = 0; k0 < K; k0 += 32) {
        __builtin_amdgcn_global_load_lds(AS1(Ap0 + k0), AS3(Ad0), 16, 0, 0);
        __builtin_amdgcn_global_load_lds(AS1(Ap1 + k0), AS3(Ad1), 16, 0, 0);
        __builtin_amdgcn_global_load_lds(AS1(Bp0 + k0), AS3(Bd0), 16, 0, 0);
        __builtin_amdgcn_global_load_lds(AS1(Bp1 + k0), AS3(Bd1), 16, 0, 0);
        __syncthreads();

        short8 af[4], bfr[4];
#pragma unroll
        for (int mi = 0; mi < 4; ++mi)
            af[mi] = *(const short8*)&Asm[(wm * 64 + mi * 16 + l15) * 32 + quad * 8];
#pragma unroll
        for (int ni = 0; ni < 4; ++ni)
            bfr[ni] = *(const short8*)&Bsm[(wn * 64 + ni * 16 + l15) * 32 + quad * 8];
#pragma unroll
        for (int mi = 0; mi < 4; ++mi)
#pragma unroll
            for (int ni = 0; ni < 4; ++ni)
                acc[mi][ni] = __builtin_amdgcn_mfma_f32_16x16x32_bf16(af[mi], bfr[ni], acc[mi][ni], 0, 0, 0);
        __syncthreads();
    }

#pragma unroll
    for (int mi = 0; mi < 4; ++mi)
#pragma unroll
        for (int ni = 0; ni < 4; ++ni)
#pragma unroll
            for (int r = 0; r < 4; ++r) {
                int row = bm + wm * 64 + mi * 16 + quad * 4 + r;
                int col = bn + wn * 64 + ni * 16 + l15;
                if (OUT_BF16)
                    ((unsigned short*)Cout)[(size_t)row * N + col] = f2bf(acc[mi][ni][r]);
                else
                    ((float*)Cout)[(size_t)row * N + col] = acc[mi][ni][r];
            }
}

// ---------------- sliding-window flash attention (S^T formulation) ----------------
// Grid (16 q-blocks, 64 b*h). 4 waves x 64 queries. Wave w computes chunks [w, w+4].
// S^T = K.Q^T  (operand swap): lane holds q=l15 (per-lane softmax stats),
// P -> PV A-fragment via ds_bpermute quad-permute (no P LDS round-trip).
// O^T = V^T.P^T: lane holds O[q=l15][d=quad*4+r].
// K/V double-buffered in LDS, one barrier per chunk, global loads prefetched.
__global__ __launch_bounds__(256) void attn_swin(const unsigned short* __restrict__ qkv,
                                                 unsigned short* __restrict__ attn_out) {
    __shared__ unsigned short Klds[2][64 * 80];
    __shared__ unsigned short Vtl[2][64 * 80];

    const int blk = blockIdx.x, bh = blockIdx.y;
    const int b = bh >> 4, h = bh & 15;
    const int tid = threadIdx.x;
    const int wave = tid >> 6, lane = tid & 63, quad = lane >> 4, l15 = lane & 15;
    const int qi_base = blk * 256 + wave * 64;
    const size_t seqbase = (size_t)b * 4096;

    // Q fragments (A-layout == B-layout of Q^T), hoisted once
    short8 qf[4][2];
#pragma unroll
    for (int qt = 0; qt < 4; ++qt)
#pragma unroll
        for (int ks = 0; ks < 2; ++ks)
            qf[qt][ks] = *(const short8*)(qkv + (seqbase + qi_base + qt * 16 + l15) * 3072
                                          + h * 64 + ks * 32 + quad * 8);

    floatx4 o[4][4];  // [qt][dt]: lane holds O[q=qt*16+l15][d=dt*16+quad*4+r]
    const floatx4 z = {0.f, 0.f, 0.f, 0.f};
    float m_run[4], l_run[4];
#pragma unroll
    for (int qt = 0; qt < 4; ++qt) {
#pragma unroll
        for (int dt = 0; dt < 4; ++dt) o[qt][dt] = z;
        m_run[qt] = -1.0e30f; l_run[qt] = 0.f;
    }

    const int kwin0 = blk * 256 - 256;
    const int sk_key = tid >> 2, sk_g = (tid & 3) * 16;
    const int sv_key = tid & 63, sv_dg = (tid >> 6) * 16;
    const float SC = 0.18033688f;  // dh^-0.5 * log2(e)

    // bpermute lane addressing (src lane = g*16+l15, g = 2*(quad&1) (+1 for addrB))
    const int addrA = (((quad & 1) << 5) + l15) << 2;
    const int addrB = addrA + 64;
    const bool hiq = quad >= 2;

    const int c0 = (kwin0 < 0) ? 4 : 0;
    int4 kvreg[4];

    auto load_kv = [&](int k0) {
        const int4* sk = (const int4*)(qkv + (seqbase + k0 + sk_key) * 3072 + 1024 + h * 64 + sk_g);
        kvreg[0] = sk[0]; kvreg[1] = sk[1];
        const int4* sv = (const int4*)(qkv + (seqbase + k0 + sv_key) * 3072 + 2048 + h * 64 + sv_dg);
        kvreg[2] = sv[0]; kvreg[3] = sv[1];
    };
    auto write_kv = [&](int buf) {
        *(int4*)&Klds[buf][sk_key * 80 + sk_g]     = kvreg[0];
        *(int4*)&Klds[buf][sk_key * 80 + sk_g + 8] = kvreg[1];
        union { unsigned short s[16]; int4 q[2]; } t;
        t.q[0] = kvreg[2]; t.q[1] = kvreg[3];
#pragma unroll
        for (int i = 0; i < 16; ++i) Vtl[buf][(sv_dg + i) * 80 + sv_key] = t.s[i];
    };

    load_kv(kwin0 + c0 * 64);
    write_kv(0);

    for (int c = c0; c < 8; ++c) {
        const int buf = (c - c0) & 1;
        __syncthreads();  // LDS buf ready for all waves
        if (c < 7) load_kv(kwin0 + (c + 1) * 64);  // prefetch overlaps compute

        if (c >= wave && c <= wave + 4) {
            // ---- S^T = K.Q^T : sT[ni][qt], lane holds key=ni*16+quad*4+r, q=qt*16+l15
            floatx4 sT[4][4];
#pragma unroll
            for (int ni = 0; ni < 4; ++ni)
#pragma unroll
                for (int qt = 0; qt < 4; ++qt) sT[ni][qt] = z;
#pragma unroll
            for (int ks = 0; ks < 2; ++ks) {
                short8 kf[4];
#pragma unroll
                for (int ni = 0; ni < 4; ++ni)
                    kf[ni] = *(const short8*)&Klds[buf][(ni * 16 + l15) * 80 + ks * 32 + quad * 8];
#pragma unroll
                for (int ni = 0; ni < 4; ++ni)
#pragma unroll
                    for (int qt = 0; qt < 4; ++qt)
                        sT[ni][qt] = __builtin_amdgcn_mfma_f32_16x16x32_bf16(kf[ni], qf[qt][ks], sT[ni][qt], 0, 0, 0);
            }

            // ---- mask diagonal chunks (local idx: key j = ni*16+quad*4+r, query i = qt*16+l15)
            if (c == wave) {            // valid iff j >= i+1
#pragma unroll
                for (int ni = 0; ni < 4; ++ni)
#pragma unroll
                    for (int qt = 0; qt < 4; ++qt) {
                        int jb = ni * 16 + quad * 4, i = qt * 16 + l15;
#pragma unroll
                        for (int r = 0; r < 4; ++r)
                            if (jb + r < i + 1) sT[ni][qt][r] = -3.0e38f;
                    }
            } else if (c == wave + 4) { // valid iff j <= i
#pragma unroll
                for (int ni = 0; ni < 4; ++ni)
#pragma unroll
                    for (int qt = 0; qt < 4; ++qt) {
                        int jb = ni * 16 + quad * 4, i = qt * 16 + l15;
#pragma unroll
                        for (int r = 0; r < 4; ++r)
                            if (jb + r > i) sT[ni][qt][r] = -3.0e38f;
                    }
            }

            // ---- V^T fragments for PV (hoisted per chunk)
            short8 vf[4][2];
#pragma unroll
            for (int dt = 0; dt < 4; ++dt)
#pragma unroll
                for (int ks = 0; ks < 2; ++ks)
                    vf[dt][ks] = *(const short8*)&Vtl[buf][(dt * 16 + l15) * 80 + ks * 32 + quad * 8];

            // ---- per query-tile: softmax + quad-permute + PV
#pragma unroll
            for (int qt = 0; qt < 4; ++qt) {
                float mx = -3.0e38f;
#pragma unroll
                for (int ni = 0; ni < 4; ++ni)
#pragma unroll
                    for (int r = 0; r < 4; ++r) mx = fmaxf(mx, sT[ni][qt][r]);
                mx = fmaxf(mx, __shfl_xor(mx, 16));
                mx = fmaxf(mx, __shfl_xor(mx, 32));
                float mn = fmaxf(m_run[qt], mx * SC);
                float alpha = __builtin_amdgcn_exp2f(m_run[qt] - mn);
                m_run[qt] = mn;

                float ls = 0.f;
                int Pk[4][2];
#pragma unroll
                for (int ni = 0; ni < 4; ++ni) {
                    float p0 = __builtin_amdgcn_exp2f(fmaf(sT[ni][qt][0], SC, -mn));
                    float p1 = __builtin_amdgcn_exp2f(fmaf(sT[ni][qt][1], SC, -mn));
                    float p2 = __builtin_amdgcn_exp2f(fmaf(sT[ni][qt][2], SC, -mn));
                    float p3 = __builtin_amdgcn_exp2f(fmaf(sT[ni][qt][3], SC, -mn));
                    ls += (p0 + p1) + (p2 + p3);
                    Pk[ni][0] = pk_bf16(p0, p1);
                    Pk[ni][1] = pk_bf16(p2, p3);
                }
                ls += __shfl_xor(ls, 16);
                ls += __shfl_xor(ls, 32);
                l_run[qt] = l_run[qt] * alpha + ls;
#pragma unroll
                for (int dt = 0; dt < 4; ++dt)
#pragma unroll
                    for (int r = 0; r < 4; ++r) o[qt][dt][r] *= alpha;

                // quad-permute P (C-layout) -> A-fragment pf[ks]: lane gets
                // P[q=l15][key=32ks+8*quad+2t+{0,1}] in reg t
#pragma unroll
                for (int ks = 0; ks < 2; ++ks) {
                    int a0 = __builtin_amdgcn_ds_bpermute(addrA, Pk[2 * ks][0]);
                    int b0 = __builtin_amdgcn_ds_bpermute(addrA, Pk[2 * ks + 1][0]);
                    int a1 = __builtin_amdgcn_ds_bpermute(addrA, Pk[2 * ks][1]);
                    int b1 = __builtin_amdgcn_ds_bpermute(addrA, Pk[2 * ks + 1][1]);
                    int a2 = __builtin_amdgcn_ds_bpermute(addrB, Pk[2 * ks][0]);
                    int b2 = __builtin_amdgcn_ds_bpermute(addrB, Pk[2 * ks + 1][0]);
                    int a3 = __builtin_amdgcn_ds_bpermute(addrB, Pk[2 * ks][1]);
                    int b3 = __builtin_amdgcn_ds_bpermute(addrB, Pk[2 * ks + 1][1]);
                    union { int i[4]; short8 v; } u;
                    u.i[0] = hiq ? b0 : a0;
                    u.i[1] = hiq ? b1 : a1;
                    u.i[2] = hiq ? b2 : a2;
                    u.i[3] = hiq ? b3 : a3;
#pragma unroll
                    for (int dt = 0; dt < 4; ++dt)
                        o[qt][dt] = __builtin_amdgcn_mfma_f32_16x16x32_bf16(vf[dt][ks], u.v, o[qt][dt], 0, 0, 0);
                }
            }
        }

        if (c < 7) write_kv(buf ^ 1);  // stage next chunk into other buffer
    }

    // ---- epilogue: O[q=l15+qt*16][d=dt*16+quad*4+r] -> packed dwordx2 stores
#pragma unroll
    for (int qt = 0; qt < 4; ++qt) {
        float rl = __builtin_amdgcn_rcpf(l_run[qt]);
        size_t rowb = (seqbase + qi_base + qt * 16 + l15) * 1024 + h * 64;
#pragma unroll
        for (int dt = 0; dt < 4; ++dt) {
            int2 val = {pk_bf16(o[qt][dt][0] * rl, o[qt][dt][1] * rl),
                        pk_bf16(o[qt][dt][2] * rl, o[qt][dt][3] * rl)};
            *(int2*)(attn_out + rowb + dt * 16 + quad * 4) = val;
        }
    }
}

extern "C" void kernel_launch(void* const* d_in, const int* in_sizes, int n_in,
                              void* d_out, int out_size, void* d_ws, size_t ws_size,
                              hipStream_t stream) {
    const float* x     = (const float*)d_in[0];  // [4,4096,1024]
    const float* w_qkv = (const float*)d_in[1];  // [1024,3072]
    const float* w_out = (const float*)d_in[2];  // [1024,1024]
    float* out = (float*)d_out;                  // [4,4096,1024]

    unsigned short* xb    = (unsigned short*)d_ws;                 // 16384*1024
    unsigned short* wqkvT = xb    + (size_t)16384 * 1024;          // 3072*1024
    unsigned short* woutT = wqkvT + (size_t)3072 * 1024;           // 1024*1024
    unsigned short* qkv   = woutT + (size_t)1024 * 1024;           // 16384*3072
    unsigned short* attn  = qkv   + (size_t)16384 * 3072;          // 16384*1024

    cvt_x<<<16384, 256, 0, stream>>>(x, xb, 4194304);
    transpose_bf16<<<dim3(96, 32), 256, 0, stream>>>(w_qkv, wqkvT, 1024, 3072);
    transpose_bf16<<<dim3(32, 32), 256, 0, stream>>>(w_out, woutT, 1024, 1024);
    gemm_bt<true><<<dim3(24, 128), 256, 0, stream>>>(xb, wqkvT, qkv, 16384, 3072, 1024);
    attn_swin<<<dim3(16, 64), 256, 0, stream>>>(qkv, attn);
    gemm_bt<false><<<dim3(8, 128), 256, 0, stream>>>(attn, woutT, out, 16384, 1024, 1024);
}

// Round 4
// 410.752 us; speedup vs baseline: 1.3951x; 1.0833x over previous
//
#include <hip/hip_runtime.h>

typedef __attribute__((ext_vector_type(8))) short short8;
typedef __attribute__((ext_vector_type(4))) float floatx4;

// int-bridge casts (generic->AS1/AS3): LDS generic addr low 32 bits = LDS offset
#define AS1(p) ((const __attribute__((address_space(1))) void*)(uintptr_t)(p))
#define AS3(p) ((__attribute__((address_space(3))) void*)(unsigned int)(uintptr_t)(p))

__device__ __forceinline__ unsigned short f2bf(float f) {
    union { float f; unsigned int u; } v; v.f = f;
    unsigned int u = v.u;
    unsigned int r = (u + 0x7FFFu + ((u >> 16) & 1u)) >> 16;
    return (unsigned short)r;
}

__device__ __forceinline__ int pk_bf16(float a, float b) {
#if __has_builtin(__builtin_amdgcn_cvt_pk_bf16_f32)
    auto r = __builtin_amdgcn_cvt_pk_bf16_f32(a, b);
    int out; __builtin_memcpy(&out, &r, sizeof(int)); return out;
#else
    return (int)f2bf(a) | ((int)f2bf(b) << 16);
#endif
}

// ---------------- convert x (fp32 -> bf16), 4 elems/thread ----------------
__global__ __launch_bounds__(256) void cvt_x(const float* __restrict__ src,
                                             unsigned short* __restrict__ dst, int n4) {
    int i = blockIdx.x * blockDim.x + threadIdx.x;
    if (i < n4) {
        float4 v = ((const float4*)src)[i];
        int2 o = {pk_bf16(v.x, v.y), pk_bf16(v.z, v.w)};
        ((int2*)dst)[i] = o;
    }
}

// ------------- transpose + convert: src[R][C] fp32 -> dst[C][R] bf16 -------------
__global__ __launch_bounds__(256) void transpose_bf16(const float* __restrict__ src,
                                                      unsigned short* __restrict__ dst,
                                                      int R, int C) {
    __shared__ float tile[32][33];
    int c0 = blockIdx.x * 32, r0 = blockIdx.y * 32;
    int tc = threadIdx.x & 31, tr = (threadIdx.x >> 5) * 4;
#pragma unroll
    for (int i = 0; i < 4; ++i)
        tile[tr + i][tc] = src[(size_t)(r0 + tr + i) * C + c0 + tc];
    __syncthreads();
#pragma unroll
    for (int i = 0; i < 4; ++i)
        dst[(size_t)(c0 + tr + i) * R + r0 + tc] = f2bf(tile[tc][tr + i]);
}

// ---------------- bf16 MFMA GEMM: C[M][N] = A[M][K] * Bt[N][K]^T ----------------
// Operand-swapped MFMA (bfr, af) -> C^T fragment layout: lane holds
// C[row = mi*16+l15][col = ni*16+quad*4 + r] -> 4 consecutive cols -> packed stores.
template <bool OUT_BF16>
__global__ __launch_bounds__(256) void gemm_bt(const unsigned short* __restrict__ A,
                                               const unsigned short* __restrict__ Bt,
                                               void* __restrict__ Cout,
                                               int M, int N, int K) {
    __shared__ unsigned short Asm[128 * 32];
    __shared__ unsigned short Bsm[128 * 32];

    const int tid = threadIdx.x;
    const int wave = tid >> 6, lane = tid & 63, quad = lane >> 4, l15 = lane & 15;
    const int wm = wave >> 1, wn = wave & 1;
    const int bm = blockIdx.y * 128, bn = blockIdx.x * 128;

    floatx4 acc[4][4];
    const floatx4 z = {0.f, 0.f, 0.f, 0.f};
#pragma unroll
    for (int mi = 0; mi < 4; ++mi)
#pragma unroll
        for (int ni = 0; ni < 4; ++ni) acc[mi][ni] = z;

    const int r0 = tid >> 2, kc = (tid & 3) * 8;
    const unsigned short* Ap0 = A + (size_t)(bm + r0) * K + kc;
    const unsigned short* Ap1 = A + (size_t)(bm + 64 + r0) * K + kc;
    const unsigned short* Bp0 = Bt + (size_t)(bn + r0) * K + kc;
    const unsigned short* Bp1 = Bt + (size_t)(bn + 64 + r0) * K + kc;
    unsigned short* Ad0 = Asm + tid * 8;
    unsigned short* Ad1 = Asm + (256 + tid) * 8;
    unsigned short* Bd0 = Bsm + tid * 8;
    unsigned short* Bd1 = Bsm + (256 + tid) * 8;

    for (int k0 = 0; k0 < K; k0 += 32) {
        __builtin_amdgcn_global_load_lds(AS1(Ap0 + k0), AS3(Ad0), 16, 0, 0);
        __builtin_amdgcn_global_load_lds(AS1(Ap1 + k0), AS3(Ad1), 16, 0, 0);
        __builtin_amdgcn_global_load_lds(AS1(Bp0 + k0), AS3(Bd0), 16, 0, 0);
        __builtin_amdgcn_global_load_lds(AS1(Bp1 + k0), AS3(Bd1), 16, 0, 0);
        __syncthreads();

        short8 af[4], bfr[4];
#pragma unroll
        for (int mi = 0; mi < 4; ++mi)
            af[mi] = *(const short8*)&Asm[(wm * 64 + mi * 16 + l15) * 32 + quad * 8];
#pragma unroll
        for (int ni = 0; ni < 4; ++ni)
            bfr[ni] = *(const short8*)&Bsm[(wn * 64 + ni * 16 + l15) * 32 + quad * 8];
#pragma unroll
        for (int mi = 0; mi < 4; ++mi)
#pragma unroll
            for (int ni = 0; ni < 4; ++ni)
                acc[mi][ni] = __builtin_amdgcn_mfma_f32_16x16x32_bf16(bfr[ni], af[mi], acc[mi][ni], 0, 0, 0);
        __syncthreads();
    }

#pragma unroll
    for (int mi = 0; mi < 4; ++mi) {
        const size_t row = (size_t)(bm + wm * 64 + mi * 16 + l15);
#pragma unroll
        for (int ni = 0; ni < 4; ++ni) {
            const size_t col = (size_t)(bn + wn * 64 + ni * 16 + quad * 4);
            if (OUT_BF16) {
                int2 val = {pk_bf16(acc[mi][ni][0], acc[mi][ni][1]),
                            pk_bf16(acc[mi][ni][2], acc[mi][ni][3])};
                *(int2*)((unsigned short*)Cout + row * N + col) = val;
            } else {
                *(float4*)((float*)Cout + row * N + col) =
                    *(const float4*)&acc[mi][ni];
            }
        }
    }
}

// ---------------- sliding-window flash attention (S^T, 32q/wave) ----------------
// Grid (32 q-blocks of 128, 64 b*h). Block: 4 waves; wave w owns 32 queries.
// Wave-pair p = w>>1 active in chunks [p, p+4] of 6 (83% busy).
// S^T = K.Q^T; softmax stats per-lane (q=l15); P->A-frag via ds_bpermute.
// K/V double-buffered (stride 72: 2-way bank alias = free), reg-prefetched.
__global__ __launch_bounds__(256, 3) void attn_swin(const unsigned short* __restrict__ qkv,
                                                    unsigned short* __restrict__ attn_out) {
    __shared__ unsigned short Klds[2][64 * 72];
    __shared__ unsigned short Vtl[2][64 * 72];

    const int blk = blockIdx.x, bh = blockIdx.y;
    const int b = bh >> 4, h = bh & 15;
    const int tid = threadIdx.x;
    const int wave = tid >> 6, lane = tid & 63, quad = lane >> 4, l15 = lane & 15;
    const int pair = wave >> 1;            // diagonal band of the wave-pair
    const int qoff = (wave & 1) * 32;      // offset within the pair's 64-q band
    const int qi_base = blk * 128 + wave * 32;
    const size_t seqbase = (size_t)b * 4096;

    // Q fragments hoisted once (A-layout == B-layout of Q^T)
    short8 qf[2][2];
#pragma unroll
    for (int qt = 0; qt < 2; ++qt)
#pragma unroll
        for (int ks = 0; ks < 2; ++ks)
            qf[qt][ks] = *(const short8*)(qkv + (seqbase + qi_base + qt * 16 + l15) * 3072
                                          + h * 64 + ks * 32 + quad * 8);

    floatx4 o[2][4];  // [qt][dt]: lane holds O[q=qt*16+l15][d=dt*16+quad*4+r]
    const floatx4 z = {0.f, 0.f, 0.f, 0.f};
    float m_run[2], l_run[2];
#pragma unroll
    for (int qt = 0; qt < 2; ++qt) {
#pragma unroll
        for (int dt = 0; dt < 4; ++dt) o[qt][dt] = z;
        m_run[qt] = -1.0e30f; l_run[qt] = 0.f;
    }

    const int kwin0 = blk * 128 - 256;
    const int c0 = (blk >= 2) ? 0 : (4 - 2 * blk);
    const int cLo = pair, cHi = pair + 4;
    const int sk_key = tid >> 2, sk_g = (tid & 3) * 16;
    const int sv_key = tid & 63, sv_dg = (tid >> 6) * 16;
    const float SC = 0.18033688f;  // dh^-0.5 * log2(e)

    // bpermute lane addressing: src lane = (quad&1)*32 + (t>>1)*16 + l15
    const int addrA = (((quad & 1) << 5) + l15) << 2;
    const int addrB = addrA + 64;
    const bool hiq = quad >= 2;

    int4 kvreg[4];
    auto load_kv = [&](int k0) {
        const int4* sk = (const int4*)(qkv + (seqbase + k0 + sk_key) * 3072 + 1024 + h * 64 + sk_g);
        kvreg[0] = sk[0]; kvreg[1] = sk[1];
        const int4* sv = (const int4*)(qkv + (seqbase + k0 + sv_key) * 3072 + 2048 + h * 64 + sv_dg);
        kvreg[2] = sv[0]; kvreg[3] = sv[1];
    };
    auto write_kv = [&](int buf) {
        *(int4*)&Klds[buf][sk_key * 72 + sk_g]     = kvreg[0];
        *(int4*)&Klds[buf][sk_key * 72 + sk_g + 8] = kvreg[1];
        union { unsigned short s[16]; int4 q[2]; } t;
        t.q[0] = kvreg[2]; t.q[1] = kvreg[3];
#pragma unroll
        for (int i = 0; i < 16; ++i) Vtl[buf][(sv_dg + i) * 72 + sv_key] = t.s[i];
    };

    load_kv(kwin0 + c0 * 64);   // == key 0 for clipped blocks
    write_kv(0);

    for (int c = c0; c < 6; ++c) {
        const int buf = (c - c0) & 1;
        __syncthreads();
        if (c < 5) load_kv(kwin0 + (c + 1) * 64);  // prefetch overlaps compute

        if (c >= cLo && c <= cHi) {
#pragma unroll
            for (int qt = 0; qt < 2; ++qt) {
                // ---- S^T = K.Q^T (kf transient per qt to cap VGPR) ----
                floatx4 sT[4];
#pragma unroll
                for (int ni = 0; ni < 4; ++ni) sT[ni] = z;
#pragma unroll
                for (int ks = 0; ks < 2; ++ks) {
#pragma unroll
                    for (int ni = 0; ni < 4; ++ni) {
                        short8 kf = *(const short8*)&Klds[buf][(ni * 16 + l15) * 72 + ks * 32 + quad * 8];
                        sT[ni] = __builtin_amdgcn_mfma_f32_16x16x32_bf16(kf, qf[qt][ks], sT[ni], 0, 0, 0);
                    }
                }

                // ---- V^T fragments early (latency hidden under softmax VALU) ----
                short8 vf[4][2];
#pragma unroll
                for (int dt = 0; dt < 4; ++dt)
#pragma unroll
                    for (int ks = 0; ks < 2; ++ks)
                        vf[dt][ks] = *(const short8*)&Vtl[buf][(dt * 16 + l15) * 72 + ks * 32 + quad * 8];

                // ---- mask diagonal chunks (key j = ni*16+quad*4+r, query i64) ----
                const int i64 = qoff + qt * 16 + l15;
                if (c == cLo) {            // valid iff j >= i64+1
#pragma unroll
                    for (int ni = 0; ni < 4; ++ni) {
                        int jb = ni * 16 + quad * 4;
#pragma unroll
                        for (int r = 0; r < 4; ++r)
                            if (jb + r < i64 + 1) sT[ni][r] = -3.0e38f;
                    }
                } else if (c == cHi) {     // valid iff j <= i64
#pragma unroll
                    for (int ni = 0; ni < 4; ++ni) {
                        int jb = ni * 16 + quad * 4;
#pragma unroll
                        for (int r = 0; r < 4; ++r)
                            if (jb + r > i64) sT[ni][r] = -3.0e38f;
                    }
                }

                // ---- online softmax (log2 domain, per-lane stats) ----
                float mx = -3.0e38f;
#pragma unroll
                for (int ni = 0; ni < 4; ++ni)
#pragma unroll
                    for (int r = 0; r < 4; ++r) mx = fmaxf(mx, sT[ni][r]);
                mx = fmaxf(mx, __shfl_xor(mx, 16));
                mx = fmaxf(mx, __shfl_xor(mx, 32));
                float mn = fmaxf(m_run[qt], mx * SC);
                float alpha = __builtin_amdgcn_exp2f(m_run[qt] - mn);
                m_run[qt] = mn;

                float ls = 0.f;
                int Pk[4][2];
#pragma unroll
                for (int ni = 0; ni < 4; ++ni) {
                    float p0 = __builtin_amdgcn_exp2f(fmaf(sT[ni][0], SC, -mn));
                    float p1 = __builtin_amdgcn_exp2f(fmaf(sT[ni][1], SC, -mn));
                    float p2 = __builtin_amdgcn_exp2f(fmaf(sT[ni][2], SC, -mn));
                    float p3 = __builtin_amdgcn_exp2f(fmaf(sT[ni][3], SC, -mn));
                    ls += (p0 + p1) + (p2 + p3);
                    Pk[ni][0] = pk_bf16(p0, p1);
                    Pk[ni][1] = pk_bf16(p2, p3);
                }
                ls += __shfl_xor(ls, 16);
                ls += __shfl_xor(ls, 32);
                l_run[qt] = l_run[qt] * alpha + ls;
#pragma unroll
                for (int dt = 0; dt < 4; ++dt)
#pragma unroll
                    for (int r = 0; r < 4; ++r) o[qt][dt][r] *= alpha;

                // ---- quad-permute P (C-layout) -> A-frag, then PV ----
#pragma unroll
                for (int ks = 0; ks < 2; ++ks) {
                    int a0 = __builtin_amdgcn_ds_bpermute(addrA, Pk[2 * ks][0]);
                    int b0 = __builtin_amdgcn_ds_bpermute(addrA, Pk[2 * ks + 1][0]);
                    int a1 = __builtin_amdgcn_ds_bpermute(addrA, Pk[2 * ks][1]);
                    int b1 = __builtin_amdgcn_ds_bpermute(addrA, Pk[2 * ks + 1][1]);
                    int a2 = __builtin_amdgcn_ds_bpermute(addrB, Pk[2 * ks][0]);
                    int b2 = __builtin_amdgcn_ds_bpermute(addrB, Pk[2 * ks + 1][0]);
                    int a3 = __builtin_amdgcn_ds_bpermute(addrB, Pk[2 * ks][1]);
                    int b3 = __builtin_amdgcn_ds_bpermute(addrB, Pk[2 * ks + 1][1]);
                    union { int i[4]; short8 v; } u;
                    u.i[0] = hiq ? b0 : a0;
                    u.i[1] = hiq ? b1 : a1;
                    u.i[2] = hiq ? b2 : a2;
                    u.i[3] = hiq ? b3 : a3;
#pragma unroll
                    for (int dt = 0; dt < 4; ++dt)
                        o[qt][dt] = __builtin_amdgcn_mfma_f32_16x16x32_bf16(vf[dt][ks], u.v, o[qt][dt], 0, 0, 0);
                }
            }
        }

        if (c < 5) write_kv(buf ^ 1);
    }

    // ---- epilogue ----
#pragma unroll
    for (int qt = 0; qt < 2; ++qt) {
        float rl = __builtin_amdgcn_rcpf(l_run[qt]);
        size_t rowb = (seqbase + qi_base + qt * 16 + l15) * 1024 + h * 64;
#pragma unroll
        for (int dt = 0; dt < 4; ++dt) {
            int2 val = {pk_bf16(o[qt][dt][0] * rl, o[qt][dt][1] * rl),
                        pk_bf16(o[qt][dt][2] * rl, o[qt][dt][3] * rl)};
            *(int2*)(attn_out + rowb + dt * 16 + quad * 4) = val;
        }
    }
}

extern "C" void kernel_launch(void* const* d_in, const int* in_sizes, int n_in,
                              void* d_out, int out_size, void* d_ws, size_t ws_size,
                              hipStream_t stream) {
    const float* x     = (const float*)d_in[0];  // [4,4096,1024]
    const float* w_qkv = (const float*)d_in[1];  // [1024,3072]
    const float* w_out = (const float*)d_in[2];  // [1024,1024]
    float* out = (float*)d_out;                  // [4,4096,1024]

    unsigned short* xb    = (unsigned short*)d_ws;                 // 16384*1024
    unsigned short* wqkvT = xb    + (size_t)16384 * 1024;          // 3072*1024
    unsigned short* woutT = wqkvT + (size_t)3072 * 1024;           // 1024*1024
    unsigned short* qkv   = woutT + (size_t)1024 * 1024;           // 16384*3072
    unsigned short* attn  = qkv   + (size_t)16384 * 3072;          // 16384*1024

    cvt_x<<<16384, 256, 0, stream>>>(x, xb, 4194304);
    transpose_bf16<<<dim3(96, 32), 256, 0, stream>>>(w_qkv, wqkvT, 1024, 3072);
    transpose_bf16<<<dim3(32, 32), 256, 0, stream>>>(w_out, woutT, 1024, 1024);
    gemm_bt<true><<<dim3(24, 128), 256, 0, stream>>>(xb, wqkvT, qkv, 16384, 3072, 1024);
    attn_swin<<<dim3(32, 64), 256, 0, stream>>>(qkv, attn);
    gemm_bt<false><<<dim3(8, 128), 256, 0, stream>>>(attn, woutT, out, 16384, 1024, 1024);
}